// Round 1
// baseline (178.910 us; speedup 1.0000x reference)
//
#include <hip/hip_runtime.h>

#define D 512
#define NTOK 512
#define BINS 64

typedef float v4f __attribute__((ext_vector_type(4)));
typedef int v4i __attribute__((ext_vector_type(4)));
typedef short short8 __attribute__((ext_vector_type(8)));

// tanh-approx gelu: x * sigmoid(1.5957691*x + 0.0713548*x^3), exp2-form.
// exp2 arg = -(log2 e)*(a x + b x^3) = x*(-2.3022082 - 0.1029437*x^2)
__device__ __forceinline__ float gelu1(float x) {
    float s = x * x;
    float q = x * __builtin_fmaf(s, -0.1029437f, -2.3022082f);
    float e = __builtin_amdgcn_exp2f(q);
    return x * __builtin_amdgcn_rcpf(1.0f + e);
}

// pack two fp32 -> two bf16 (truncation; bias < 2^-9 relative, OK per threshold)
__device__ __forceinline__ int pk2(float a, float b) {
    unsigned ua = __builtin_bit_cast(unsigned, a) >> 16;
    unsigned ub = __builtin_bit_cast(unsigned, b) & 0xffff0000u;
    return (int)(ua | ub);
}

// hi[n][e] = sum_d x[n][d]*W1[d][e] + b1[e] ; hj[n][e] = sum_d x[n][d]*W1[512+d][e]
// grid (128,4): 4 n-rows x 256 e-cols per block; thread = 1 n x 4 e.
__global__ __launch_bounds__(256) void k_proj(const float* __restrict__ x,
                                              const float* __restrict__ W1,
                                              const float* __restrict__ b1,
                                              float* __restrict__ hi,
                                              float* __restrict__ hj) {
    __shared__ float xs[4 * D];
    const int t = threadIdx.x;
    const int n0 = blockIdx.x * 4;
    const int e0 = blockIdx.y * 256;  // 0,256,512,768 -> half uniform per block
    const v4f* xg = (const v4f*)(x + (size_t)n0 * D);
    v4f* xls = (v4f*)xs;
    xls[t] = xg[t];
    xls[t + 256] = xg[t + 256];
    __syncthreads();

    const int nsub = t >> 6;
    const int e = e0 + ((t & 63) << 2);
    const int half = e >> 9;
    const int col = e & 511;
    const float* Wp = W1 + (size_t)half * D * D + col;
    v4f acc = {0.f, 0.f, 0.f, 0.f};
    if (half == 0) acc = *(const v4f*)(b1 + col);
    const float* xrow = xs + nsub * D;
    for (int d = 0; d < D; d += 4) {
        v4f xv = *(const v4f*)(xrow + d);
        v4f w0 = *(const v4f*)(Wp + (size_t)(d + 0) * D);
        v4f w1 = *(const v4f*)(Wp + (size_t)(d + 1) * D);
        v4f w2 = *(const v4f*)(Wp + (size_t)(d + 2) * D);
        v4f w3 = *(const v4f*)(Wp + (size_t)(d + 3) * D);
        acc += xv.x * w0;
        acc += xv.y * w1;
        acc += xv.z * w2;
        acc += xv.w * w3;
    }
    float* dst = (half == 0 ? hi : hj) + (size_t)(n0 + nsub) * D + col;
    *(v4f*)dst = acc;
}

// Pack W2 [512][64] fp32 -> bf16 MFMA B-fragments.
// Bp[((kt*4+nt)*64 + lane)] = 8 bf16: W2[kt*32 + (lane>>4)*8 + u][nt*16 + (lane&15)]
__global__ __launch_bounds__(256) void k_pack(const float* __restrict__ W2,
                                              short8* __restrict__ Bp) {
    const int tid = blockIdx.x * 256 + threadIdx.x;  // 0..4095
    const int l = tid & 63;
    const int nt = (tid >> 6) & 3;
    const int kt = tid >> 8;
    const int colp = nt * 16 + (l & 15);
    const int krow = kt * 32 + (l >> 4) * 8;
    short8 v;
#pragma unroll
    for (int u = 0; u < 8; ++u) {
        unsigned uf = __builtin_bit_cast(unsigned, W2[(size_t)(krow + u) * BINS + colp]);
        uf += 0x7fffu + ((uf >> 16) & 1u);  // RTN
        v[u] = (short)(uf >> 16);
    }
    Bp[tid] = v;
}

// Main fused kernel: block = 16i x 16j tile, 4 waves; wave w: i = i0+4w..+3.
// M-tile of MFMA = 16 j's (m = lane&15 = j-offset), N = 64 bins = 4 n-tiles.
__global__ __launch_bounds__(256, 4) void k_main(const float* __restrict__ hi,
                                                 const float* __restrict__ hj,
                                                 const v4i* __restrict__ Bp,
                                                 const float* __restrict__ b2,
                                                 float* __restrict__ out) {
    const int l = threadIdx.x & 63;
    const int w = threadIdx.x >> 6;
    const int c = l & 15;   // MFMA col: A m-index (j-offset) / B,D n-offset
    const int q = l >> 4;   // quad: k-group for A/B, row-group for D
    const int i0 = (blockIdx.x >> 5) * 16 + w * 4;
    const int j0 = (blockIdx.x & 31) * 16;

    v4f acc[4][4] = {};  // [p(i)][nt]

    const float* hjrow = hj + (size_t)(j0 + c) * D;
    const float* hibase = hi + (size_t)i0 * D;

    for (int kk = 0; kk < D; kk += 32) {
        const int kb = kk + q * 8;
        v4f hj0 = *(const v4f*)(hjrow + kb);
        v4f hj1 = *(const v4f*)(hjrow + kb + 4);
        short8 bf[4];
        const int kt4 = (kk >> 5) << 2;
#pragma unroll
        for (int nt = 0; nt < 4; ++nt)
            bf[nt] = __builtin_bit_cast(short8, Bp[(kt4 + nt) * 64 + l]);
#pragma unroll
        for (int p = 0; p < 4; ++p) {
            const float* hirow = hibase + (size_t)p * D;
            v4f a0 = *(const v4f*)(hirow + kb);
            v4f a1 = *(const v4f*)(hirow + kb + 4);
            float g0 = gelu1(a0.x + hj0.x);
            float g1 = gelu1(a0.y + hj0.y);
            float g2 = gelu1(a0.z + hj0.z);
            float g3 = gelu1(a0.w + hj0.w);
            float g4 = gelu1(a1.x + hj1.x);
            float g5 = gelu1(a1.y + hj1.y);
            float g6 = gelu1(a1.z + hj1.z);
            float g7 = gelu1(a1.w + hj1.w);
            v4i ai = {pk2(g0, g1), pk2(g2, g3), pk2(g4, g5), pk2(g6, g7)};
            short8 af = __builtin_bit_cast(short8, ai);
#pragma unroll
            for (int nt = 0; nt < 4; ++nt)
                acc[p][nt] = __builtin_amdgcn_mfma_f32_16x16x32_bf16(af, bf[nt], acc[p][nt], 0, 0, 0);
        }
    }

#pragma unroll
    for (int p = 0; p < 4; ++p) {
        const size_t rowbase = ((size_t)(i0 + p) * NTOK + j0 + q * 4) * BINS;
#pragma unroll
        for (int nt = 0; nt < 4; ++nt) {
            const float bb = b2[nt * 16 + c];
            float* op = out + rowbase + nt * 16 + c;
#pragma unroll
            for (int r = 0; r < 4; ++r)
                op[(size_t)r * BINS] = acc[p][nt][r] + bb;
        }
    }
}

extern "C" void kernel_launch(void* const* d_in, const int* in_sizes, int n_in,
                              void* d_out, int out_size, void* d_ws, size_t ws_size,
                              hipStream_t stream) {
    const float* x  = (const float*)d_in[0];
    const float* W1 = (const float*)d_in[1];
    const float* b1 = (const float*)d_in[2];
    const float* W2 = (const float*)d_in[3];
    const float* b2 = (const float*)d_in[4];
    float* out = (float*)d_out;

    char* ws = (char*)d_ws;
    float* hi = (float*)ws;                    // 1 MB
    float* hj = (float*)(ws + (1u << 20));     // 1 MB
    short8* Bp = (short8*)(ws + (2u << 20));   // 64 KB

    k_proj<<<dim3(128, 4), 256, 0, stream>>>(x, W1, b1, hi, hj);
    k_pack<<<16, 256, 0, stream>>>(W2, Bp);
    k_main<<<1024, 256, 0, stream>>>(hi, hj, (const v4i*)Bp, b2, out);
}

// Round 2
// 170.317 us; speedup vs baseline: 1.0505x; 1.0505x over previous
//
#include <hip/hip_runtime.h>

#define D 512
#define NTOK 512
#define BINS 64

typedef float v4f __attribute__((ext_vector_type(4)));
typedef int v4i __attribute__((ext_vector_type(4)));
typedef short short8 __attribute__((ext_vector_type(8)));

// tanh-approx gelu: x * sigmoid(1.5957691*x + 0.0713548*x^3), exp2-form.
__device__ __forceinline__ float gelu1(float x) {
    float s = x * x;
    float q = x * __builtin_fmaf(s, -0.1029437f, -2.3022082f);
    float e = __builtin_amdgcn_exp2f(q);
    return x * __builtin_amdgcn_rcpf(1.0f + e);
}

// pack two fp32 -> two bf16 (truncation; bias < 2^-9 relative)
__device__ __forceinline__ int pk2(float a, float b) {
    unsigned ua = __builtin_bit_cast(unsigned, a) >> 16;
    unsigned ub = __builtin_bit_cast(unsigned, b) & 0xffff0000u;
    return (int)(ua | ub);
}

// Stage 1: hi[n][e] = x[n][:] @ W1[:512][:,e] + b1[e];  hj[n][e] = x[n][:] @ W1[512:][:,e]
// W-streaming: lanes hold 4 contiguous output cols (1KB/instr coalesced W read);
// x values are wave-uniform -> scalar loads; 2 rows per wave.
// grid (64, 4): block = 8 rows x 256 cols; wave w: rows blockIdx.x*8 + w*2 + {0,1}.
__global__ __launch_bounds__(256) void k_proj(const float* __restrict__ x,
                                              const float* __restrict__ W1,
                                              const float* __restrict__ b1,
                                              float* __restrict__ hi,
                                              float* __restrict__ hj) {
    const int l = threadIdx.x & 63;
    const int w = __builtin_amdgcn_readfirstlane(threadIdx.x >> 6);
    const int m0 = blockIdx.x * 8 + w * 2;
    const int n = blockIdx.y * 256 + l * 4;  // 256-col groups never straddle the half boundary
    const int half = n >> 9;
    const int col = n & 511;
    const float* Wp = W1 + (size_t)half * (D * D) + col;
    const float* x0 = x + (size_t)m0 * D;
    const float* x1 = x0 + D;
    v4f acc0 = {0.f, 0.f, 0.f, 0.f}, acc1 = {0.f, 0.f, 0.f, 0.f};
    if (half == 0) { acc0 = *(const v4f*)(b1 + col); acc1 = acc0; }
#pragma unroll 8
    for (int k = 0; k < D; ++k) {
        v4f wv = *(const v4f*)(Wp + (size_t)k * D);
        float a0 = x0[k];  // uniform address -> s_load
        float a1 = x1[k];
        acc0 += a0 * wv;
        acc1 += a1 * wv;
    }
    float* dst = (half ? hj : hi) + (size_t)m0 * D + col;
    *(v4f*)dst = acc0;
    *(v4f*)(dst + D) = acc1;
}

// Pack W2 [512][64] fp32 -> bf16 MFMA B-fragments (RTN).
// Bp[(kt*4+nt)*64 + lane] = 8 bf16: W2[kt*32 + (lane>>4)*8 + u][nt*16 + (lane&15)]
__global__ __launch_bounds__(256) void k_pack(const float* __restrict__ W2,
                                              short8* __restrict__ Bp) {
    const int tid = blockIdx.x * 256 + threadIdx.x;  // 0..4095
    const int l = tid & 63;
    const int nt = (tid >> 6) & 3;
    const int kt = tid >> 8;
    const int colp = nt * 16 + (l & 15);
    const int krow = kt * 32 + (l >> 4) * 8;
    short8 v;
#pragma unroll
    for (int u = 0; u < 8; ++u) {
        unsigned uf = __builtin_bit_cast(unsigned, W2[(size_t)(krow + u) * BINS + colp]);
        uf += 0x7fffu + ((uf >> 16) & 1u);  // RTN
        v[u] = (short)(uf >> 16);
    }
    Bp[tid] = v;
}

// Main fused kernel: grid 2048; block covers 8 i x 16 j via 4 waves (2 i-rows each).
// MFMA m-dim = 16 j's (m = lane&15), n-dim = bins (4 tiles of 16), K = D.
// p=2 i-rows/wave: acc = 32 regs -> ~5-6 waves/SIMD occupancy.
__global__ __launch_bounds__(256) void k_main(const float* __restrict__ hi,
                                              const float* __restrict__ hj,
                                              const v4i* __restrict__ Bp,
                                              const float* __restrict__ b2,
                                              float* __restrict__ out) {
    const int l = threadIdx.x & 63;
    const int w = threadIdx.x >> 6;
    const int c = l & 15;   // MFMA col: A m-index (j-offset) / B,D n-offset
    const int q = l >> 4;   // quad: k-group for A/B, row-group for D
    const int i0 = (blockIdx.x >> 5) * 8 + w * 2;
    const int j0 = (blockIdx.x & 31) * 16;

    v4f acc[2][4] = {};  // [p(i)][nt]

    const float* hjrow = hj + (size_t)(j0 + c) * D;
    const float* hibase = hi + (size_t)i0 * D;

    for (int kk = 0; kk < D; kk += 32) {
        const int kb = kk + q * 8;
        v4f hj0 = *(const v4f*)(hjrow + kb);
        v4f hj1 = *(const v4f*)(hjrow + kb + 4);
        short8 bf[4];
        const int kt4 = (kk >> 5) << 2;
#pragma unroll
        for (int nt = 0; nt < 4; ++nt)
            bf[nt] = __builtin_bit_cast(short8, Bp[(kt4 + nt) * 64 + l]);
#pragma unroll
        for (int p = 0; p < 2; ++p) {
            const float* hirow = hibase + (size_t)p * D;
            v4f a0 = *(const v4f*)(hirow + kb);
            v4f a1 = *(const v4f*)(hirow + kb + 4);
            float g0 = gelu1(a0.x + hj0.x);
            float g1 = gelu1(a0.y + hj0.y);
            float g2 = gelu1(a0.z + hj0.z);
            float g3 = gelu1(a0.w + hj0.w);
            float g4 = gelu1(a1.x + hj1.x);
            float g5 = gelu1(a1.y + hj1.y);
            float g6 = gelu1(a1.z + hj1.z);
            float g7 = gelu1(a1.w + hj1.w);
            v4i ai = {pk2(g0, g1), pk2(g2, g3), pk2(g4, g5), pk2(g6, g7)};
            short8 af = __builtin_bit_cast(short8, ai);
#pragma unroll
            for (int nt = 0; nt < 4; ++nt)
                acc[p][nt] = __builtin_amdgcn_mfma_f32_16x16x32_bf16(af, bf[nt], acc[p][nt], 0, 0, 0);
        }
    }

#pragma unroll
    for (int p = 0; p < 2; ++p) {
        const size_t rowbase = ((size_t)(i0 + p) * NTOK + j0 + q * 4) * BINS;
#pragma unroll
        for (int nt = 0; nt < 4; ++nt) {
            const float bb = b2[nt * 16 + c];
            float* op = out + rowbase + nt * 16 + c;
#pragma unroll
            for (int r = 0; r < 4; ++r)
                op[(size_t)r * BINS] = acc[p][nt][r] + bb;
        }
    }
}

extern "C" void kernel_launch(void* const* d_in, const int* in_sizes, int n_in,
                              void* d_out, int out_size, void* d_ws, size_t ws_size,
                              hipStream_t stream) {
    const float* x  = (const float*)d_in[0];
    const float* W1 = (const float*)d_in[1];
    const float* b1 = (const float*)d_in[2];
    const float* W2 = (const float*)d_in[3];
    const float* b2 = (const float*)d_in[4];
    float* out = (float*)d_out;

    char* ws = (char*)d_ws;
    float* hi = (float*)ws;                    // 1 MB
    float* hj = (float*)(ws + (1u << 20));     // 1 MB
    short8* Bp = (short8*)(ws + (2u << 20));   // 64 KB

    k_proj<<<dim3(64, 4), 256, 0, stream>>>(x, W1, b1, hi, hj);
    k_pack<<<16, 256, 0, stream>>>(W2, Bp);
    k_main<<<2048, 256, 0, stream>>>(hi, hj, (const v4i*)Bp, b2, out);
}

// Round 3
// 166.359 us; speedup vs baseline: 1.0754x; 1.0238x over previous
//
#include <hip/hip_runtime.h>

#define D 512
#define NTOK 512
#define BINS 64

typedef float v4f __attribute__((ext_vector_type(4)));
typedef int v4i __attribute__((ext_vector_type(4)));
typedef short short8 __attribute__((ext_vector_type(8)));

// tanh-approx gelu: x * sigmoid(1.5957691*x + 0.0713548*x^3), exp2-form.
__device__ __forceinline__ float gelu1(float x) {
    float s = x * x;
    float q = x * __builtin_fmaf(s, -0.1029437f, -2.3022082f);
    float e = __builtin_amdgcn_exp2f(q);
    return x * __builtin_amdgcn_rcpf(1.0f + e);
}

// pack two fp32 -> two bf16 (truncation; bias < 2^-9 relative)
__device__ __forceinline__ int pk2(float a, float b) {
    unsigned ua = __builtin_bit_cast(unsigned, a) >> 16;
    unsigned ub = __builtin_bit_cast(unsigned, b) & 0xffff0000u;
    return (int)(ua | ub);
}

// Fused stage-1 projection + W2 fragment pack.
// Blocks 0..255: proj. bx=b&63 -> 8 rows, by=b>>6 -> 256 cols. 8 waves, 1 row/wave,
// lane holds 4 contiguous cols (1KB/instr coalesced W1 read), x via scalar loads.
// Blocks 256..263: pack W2 [512][64] fp32 -> bf16 MFMA B-fragments (RTN).
__global__ __launch_bounds__(512) void k_proj(const float* __restrict__ x,
                                              const float* __restrict__ W1,
                                              const float* __restrict__ b1,
                                              const float* __restrict__ W2,
                                              float* __restrict__ hi,
                                              float* __restrict__ hj,
                                              short8* __restrict__ Bp) {
    const int b = blockIdx.x;
    if (b >= 256) {
        const int tid = (b - 256) * 512 + threadIdx.x;  // 0..4095
        const int l = tid & 63;
        const int nt = (tid >> 6) & 3;
        const int kt = tid >> 8;
        const int colp = nt * 16 + (l & 15);
        const int krow = kt * 32 + (l >> 4) * 8;
        short8 v;
#pragma unroll
        for (int u = 0; u < 8; ++u) {
            unsigned uf = __builtin_bit_cast(unsigned, W2[(size_t)(krow + u) * BINS + colp]);
            uf += 0x7fffu + ((uf >> 16) & 1u);  // RTN
            v[u] = (short)(uf >> 16);
        }
        Bp[tid] = v;
        return;
    }
    const int bx = b & 63, by = b >> 6;
    const int l = threadIdx.x & 63;
    const int w = __builtin_amdgcn_readfirstlane(threadIdx.x >> 6);
    const int m = bx * 8 + w;
    const int n = by * 256 + l * 4;  // never straddles the half boundary
    const int half = n >> 9;
    const int col = n & 511;
    const float* Wp = W1 + (size_t)half * (D * D) + col;
    const float* xr = x + (size_t)m * D;  // wave-uniform -> s_load
    v4f acc = {0.f, 0.f, 0.f, 0.f};
    if (half == 0) acc = *(const v4f*)(b1 + col);
#pragma unroll 16
    for (int k = 0; k < D; ++k) {
        v4f wv = *(const v4f*)(Wp + (size_t)k * D);
        acc += xr[k] * wv;
    }
    *(v4f*)((half ? hj : hi) + (size_t)m * D + col) = acc;
}

// Main fused kernel: grid 1024; block tile 16i x 16j, 4 waves, 4 i-rows/wave.
// hi/hj staged per 64-k chunk in LDS (coalesced coop load, register-prefetched);
// fragments read via ds_read_b128 (hi = broadcast, conflict-free; hj = padded).
__global__ __launch_bounds__(256) void k_main(const float* __restrict__ hi,
                                              const float* __restrict__ hj,
                                              const v4i* __restrict__ Bp,
                                              const float* __restrict__ b2,
                                              float* __restrict__ out) {
    const int l = threadIdx.x & 63;
    const int w = threadIdx.x >> 6;
    const int c = l & 15;   // MFMA col: A m-index (j-offset) / B,D n-offset
    const int q = l >> 4;   // quad: k-group for A/B, row-group for D
    const int ib = (blockIdx.x >> 5) * 16;
    const int j0 = (blockIdx.x & 31) * 16;

    __shared__ float hi_c[16][68];  // pad 4: keeps 16B align, spreads banks
    __shared__ float hj_c[16][68];

    const int r = threadIdx.x >> 4;          // coop-load row 0..15
    const int s4 = (threadIdx.x & 15) * 4;   // coop-load col offset
    const float* gih = hi + (size_t)(ib + r) * D + s4;
    const float* gjh = hj + (size_t)(j0 + r) * D + s4;

    v4f acc[4][4] = {};  // [p(i)][nt]

    v4f pi = *(const v4f*)gih;  // prefetch chunk 0
    v4f pj = *(const v4f*)gjh;

    for (int chunk = 0; chunk < 8; ++chunk) {
        *(v4f*)&hi_c[r][s4] = pi;
        *(v4f*)&hj_c[r][s4] = pj;
        __syncthreads();
        if (chunk < 7) {  // prefetch next chunk under this chunk's compute
            pi = *(const v4f*)(gih + (chunk + 1) * 64);
            pj = *(const v4f*)(gjh + (chunk + 1) * 64);
        }
        const int kt4 = chunk * 8;
#pragma unroll
        for (int h = 0; h < 2; ++h) {
            const int kb = h * 32 + q * 8;
            v4f hj0 = *(const v4f*)&hj_c[c][kb];
            v4f hj1 = *(const v4f*)&hj_c[c][kb + 4];
            short8 bf[4];
#pragma unroll
            for (int nt = 0; nt < 4; ++nt)
                bf[nt] = __builtin_bit_cast(short8, Bp[(kt4 + h * 4 + nt) * 64 + l]);
#pragma unroll
            for (int p = 0; p < 4; ++p) {
                v4f a0 = *(const v4f*)&hi_c[w * 4 + p][kb];
                v4f a1 = *(const v4f*)&hi_c[w * 4 + p][kb + 4];
                float g0 = gelu1(a0.x + hj0.x);
                float g1 = gelu1(a0.y + hj0.y);
                float g2 = gelu1(a0.z + hj0.z);
                float g3 = gelu1(a0.w + hj0.w);
                float g4 = gelu1(a1.x + hj1.x);
                float g5 = gelu1(a1.y + hj1.y);
                float g6 = gelu1(a1.z + hj1.z);
                float g7 = gelu1(a1.w + hj1.w);
                v4i ai = {pk2(g0, g1), pk2(g2, g3), pk2(g4, g5), pk2(g6, g7)};
                short8 af = __builtin_bit_cast(short8, ai);
#pragma unroll
                for (int nt = 0; nt < 4; ++nt)
                    acc[p][nt] = __builtin_amdgcn_mfma_f32_16x16x32_bf16(af, bf[nt], acc[p][nt], 0, 0, 0);
            }
        }
        __syncthreads();
    }

    const int i0 = ib + w * 4;
#pragma unroll
    for (int p = 0; p < 4; ++p) {
        const size_t rowbase = ((size_t)(i0 + p) * NTOK + j0 + q * 4) * BINS;
#pragma unroll
        for (int nt = 0; nt < 4; ++nt) {
            const float bb = b2[nt * 16 + c];
            float* op = out + rowbase + nt * 16 + c;
#pragma unroll
            for (int rr = 0; rr < 4; ++rr)
                op[(size_t)rr * BINS] = acc[p][nt][rr] + bb;
        }
    }
}

extern "C" void kernel_launch(void* const* d_in, const int* in_sizes, int n_in,
                              void* d_out, int out_size, void* d_ws, size_t ws_size,
                              hipStream_t stream) {
    const float* x  = (const float*)d_in[0];
    const float* W1 = (const float*)d_in[1];
    const float* b1 = (const float*)d_in[2];
    const float* W2 = (const float*)d_in[3];
    const float* b2 = (const float*)d_in[4];
    float* out = (float*)d_out;

    char* ws = (char*)d_ws;
    float* hi = (float*)ws;                    // 1 MB
    float* hj = (float*)(ws + (1u << 20));     // 1 MB
    short8* Bp = (short8*)(ws + (2u << 20));   // 64 KB

    k_proj<<<264, 512, 0, stream>>>(x, W1, b1, W2, hi, hj, Bp);
    k_main<<<1024, 256, 0, stream>>>(hi, hj, (const v4i*)Bp, b2, out);
}

// Round 4
// 152.056 us; speedup vs baseline: 1.1766x; 1.0941x over previous
//
#include <hip/hip_runtime.h>
#include <hip/hip_fp16.h>

#define D 512
#define NTOK 512
#define BINS 64

typedef float v4f __attribute__((ext_vector_type(4)));
typedef int v4i __attribute__((ext_vector_type(4)));
typedef short short8 __attribute__((ext_vector_type(8)));
typedef _Float16 h8 __attribute__((ext_vector_type(8)));
typedef _Float16 h4 __attribute__((ext_vector_type(4)));

// packed f16 tanh-approx gelu: x * sigmoid(1.5957691x + 0.0713548x^3), exp2 form.
// f16 saturation gives correct limits: e=inf -> rcp=0 -> gelu=0 (x<<0);
// e->0 -> rcp(1)=1 -> gelu=x (x>>0).
__device__ __forceinline__ __half2 gelu2(__half2 x) {
    __half2 s = __hmul2(x, x);
    __half2 q = __hmul2(x, __hfma2(s, __float2half2_rn(-0.1029437f),
                                      __float2half2_rn(-2.3022082f)));
    __half2 e = h2exp2(q);
    __half2 r = h2rcp(__hadd2(e, __float2half2_rn(1.0f)));
    return __hmul2(x, r);
}

__device__ __forceinline__ __half2 bc_h2(int v) { return __builtin_bit_cast(__half2, v); }
__device__ __forceinline__ int bc_i(__half2 v) { return __builtin_bit_cast(int, v); }

// Fused stage-1 projection (fp32 math, f16 output) + W2 f16 fragment pack.
// Blocks 0..511: proj. rb=b>>4 -> 16 rows, cg=b&15 -> 64 cols (of 1024 combined).
//   x row-block staged in LDS; lane = 1 row x 4 cols; W1 streamed (1KB-class loads).
// Blocks 512..527: pack W2 [512][64] -> f16 MFMA B-fragments.
__global__ __launch_bounds__(256) void k_proj(const float* __restrict__ x,
                                              const float* __restrict__ W1,
                                              const float* __restrict__ b1,
                                              const float* __restrict__ W2,
                                              __half* __restrict__ hi,
                                              __half* __restrict__ hj,
                                              short8* __restrict__ Bp) {
    const int b = blockIdx.x;
    if (b >= 512) {
        const int tid = (b - 512) * 256 + threadIdx.x;  // 0..4095
        const int ll = tid & 63;
        const int nt = (tid >> 6) & 3;
        const int kt = tid >> 8;
        const int colp = nt * 16 + (ll & 15);
        const int krow = kt * 32 + (ll >> 4) * 8;
        short8 v;
#pragma unroll
        for (int u = 0; u < 8; ++u) {
            _Float16 hv = (_Float16)W2[(size_t)(krow + u) * BINS + colp];  // RTE
            v[u] = __builtin_bit_cast(short, hv);
        }
        Bp[tid] = v;
        return;
    }
    const int rb = b >> 4, cg = b & 15;
    __shared__ __align__(16) float xs[16][516];  // +4 pad: conflict-free reads
    const float* xsrc = x + (size_t)rb * 16 * D;
#pragma unroll
    for (int i = 0; i < 8; ++i) {
        int e = (threadIdx.x + 256 * i) * 4;
        *(v4f*)&xs[e >> 9][e & 511] = *(const v4f*)(xsrc + e);
    }
    __syncthreads();

    const int l = threadIdx.x & 63;
    const int w = threadIdx.x >> 6;
    const int row = w * 4 + (l >> 4);       // 0..15
    const int col4 = (l & 15) * 4;
    const int half = cg >> 3;
    const int e0 = (cg & 7) * 64 + col4;
    const float* Wp = W1 + (size_t)half * (D * D) + e0;
    v4f acc = {0.f, 0.f, 0.f, 0.f};
    if (half == 0) acc = *(const v4f*)(b1 + e0);
#pragma unroll 4
    for (int k = 0; k < D; k += 4) {
        v4f xa = *(const v4f*)&xs[row][k];
        v4f w0 = *(const v4f*)(Wp + (size_t)(k + 0) * D);
        v4f w1 = *(const v4f*)(Wp + (size_t)(k + 1) * D);
        v4f w2 = *(const v4f*)(Wp + (size_t)(k + 2) * D);
        v4f w3 = *(const v4f*)(Wp + (size_t)(k + 3) * D);
        acc += xa.x * w0;
        acc += xa.y * w1;
        acc += xa.z * w2;
        acc += xa.w * w3;
    }
    h4 o;
    o[0] = (_Float16)acc.x; o[1] = (_Float16)acc.y;
    o[2] = (_Float16)acc.z; o[3] = (_Float16)acc.w;
    __half* dst = (half ? hj : hi) + (size_t)(rb * 16 + row) * D + e0;
    *(h4*)dst = o;
}

// Main fused kernel: grid 1024; tile 16i x 16j, 4 waves, 4 i-rows/wave.
// f16 hi/hj staged per 64-k chunk in LDS; packed-f16 gelu feeds f16 MFMA directly.
__global__ __launch_bounds__(256) void k_main(const __half* __restrict__ hi,
                                              const __half* __restrict__ hj,
                                              const v4i* __restrict__ Bp,
                                              const float* __restrict__ b2,
                                              float* __restrict__ out) {
    const int l = threadIdx.x & 63;
    const int w = threadIdx.x >> 6;
    const int c = l & 15;   // MFMA col: A m-index (j-offset) / B,D n-offset
    const int q = l >> 4;   // quad: k-group for A/B, row-group for D
    const int ib = (blockIdx.x >> 5) * 16;
    const int j0 = (blockIdx.x & 31) * 16;

    __shared__ __align__(16) short hic[16][72];  // 72 f16 row stride (16B-aligned rows)
    __shared__ __align__(16) short hjc[16][72];

    const int t = threadIdx.x;
    const int lr = (t & 127) >> 3;      // 0..15
    const int lc = (t & 7) * 8;         // f16 col 0..56
    const __half* gsrc = (t < 128 ? hi + (size_t)(ib + lr) * D
                                  : hj + (size_t)(j0 + lr) * D) + lc;
    short* ldst = (t < 128 ? &hic[lr][lc] : &hjc[lr][lc]);

    v4f acc[4][4] = {};  // [p(i)][nt]
    v4i pf = *(const v4i*)gsrc;  // prefetch chunk 0 (16B = 8 f16)

    for (int chunk = 0; chunk < 8; ++chunk) {
        *(v4i*)ldst = pf;
        __syncthreads();
        if (chunk < 7) pf = *(const v4i*)(gsrc + (chunk + 1) * 64);
        const int kt4 = chunk * 8;
#pragma unroll
        for (int h = 0; h < 2; ++h) {
            const int ko = h * 32 + q * 8;
            v4i hjraw = *(const v4i*)&hjc[c][ko];
            __half2 j0h = bc_h2(hjraw.x), j1h = bc_h2(hjraw.y);
            __half2 j2h = bc_h2(hjraw.z), j3h = bc_h2(hjraw.w);
            v4i bfr[4];
#pragma unroll
            for (int nt = 0; nt < 4; ++nt)
                bfr[nt] = Bp[(kt4 + h * 4 + nt) * 64 + l];
#pragma unroll
            for (int p = 0; p < 4; ++p) {
                v4i ar = *(const v4i*)&hic[w * 4 + p][ko];
                __half2 g0 = gelu2(__hadd2(bc_h2(ar.x), j0h));
                __half2 g1 = gelu2(__hadd2(bc_h2(ar.y), j1h));
                __half2 g2 = gelu2(__hadd2(bc_h2(ar.z), j2h));
                __half2 g3 = gelu2(__hadd2(bc_h2(ar.w), j3h));
                v4i ai = {bc_i(g0), bc_i(g1), bc_i(g2), bc_i(g3)};
                h8 af = __builtin_bit_cast(h8, ai);
#pragma unroll
                for (int nt = 0; nt < 4; ++nt)
                    acc[p][nt] = __builtin_amdgcn_mfma_f32_16x16x32_f16(
                        af, __builtin_bit_cast(h8, bfr[nt]), acc[p][nt], 0, 0, 0);
            }
        }
        __syncthreads();
    }

    const int i0 = ib + w * 4;
#pragma unroll
    for (int p = 0; p < 4; ++p) {
        const size_t rowbase = ((size_t)(i0 + p) * NTOK + j0 + q * 4) * BINS;
#pragma unroll
        for (int nt = 0; nt < 4; ++nt) {
            const float bb = b2[nt * 16 + c];
            float* op = out + rowbase + nt * 16 + c;
#pragma unroll
            for (int rr = 0; rr < 4; ++rr)
                op[(size_t)rr * BINS] = acc[p][nt][rr] + bb;
        }
    }
}

extern "C" void kernel_launch(void* const* d_in, const int* in_sizes, int n_in,
                              void* d_out, int out_size, void* d_ws, size_t ws_size,
                              hipStream_t stream) {
    const float* x  = (const float*)d_in[0];
    const float* W1 = (const float*)d_in[1];
    const float* b1 = (const float*)d_in[2];
    const float* W2 = (const float*)d_in[3];
    const float* b2 = (const float*)d_in[4];
    float* out = (float*)d_out;

    char* ws = (char*)d_ws;
    __half* hi = (__half*)ws;                     // 512 KB
    __half* hj = (__half*)(ws + (512u << 10));    // 512 KB
    short8* Bp = (short8*)(ws + (1u << 20));      // 64 KB

    k_proj<<<528, 256, 0, stream>>>(x, W1, b1, W2, hi, hj, Bp);
    k_main<<<1024, 256, 0, stream>>>(hi, hj, (const v4i*)Bp, b2, out);
}